// Round 3
// baseline (350.201 us; speedup 1.0000x reference)
//
#include <hip/hip_runtime.h>
#include <hip/hip_bf16.h>
#include <stdint.h>

// B=2, S=2048, D=1024, H=16, HD=64.
// RESOLVED dtypes (round-1/2 A/B): all inputs fp32 (reading them as bf16
// NaN'd; converting fp32->bf16 didn't), d_out is fp32 (bf16 writes into it
// reproduced the exact sqrt(2)*refmax packing-error signature in round 2).
// Compute pipeline: fp32 inputs canonicalized to bf16 once, then bf16 MFMA
// GEMMs + flash attention, fp32 accumulation, fp32 final store.
#define Bb 2
#define Ss 2048
#define Dd 1024
#define Hh 16
#define HD 64

typedef __attribute__((ext_vector_type(8))) __bf16 bf16x8;
typedef __attribute__((ext_vector_type(4))) float f32x4;

// ---- workspace layout (bf16 elements) --------------------------------------
#define HS_N   (Bb * Ss * Dd)          // 4194304
#define W_N    (Dd * Dd)               // 1048576
#define B_N    (Dd)                    // 1024
#define CAN_HS 0
#define CAN_WQ (CAN_HS + HS_N)
#define CAN_BQ (CAN_WQ + W_N)
#define CAN_WK (CAN_BQ + B_N)
#define CAN_BK (CAN_WK + W_N)
#define CAN_WV (CAN_BK + B_N)
#define CAN_BV (CAN_WV + W_N)
#define CAN_WO (CAN_BV + B_N)
#define CAN_BO (CAN_WO + W_N)
#define CAN_END (CAN_BO + B_N)         // 8392704
#define TSZ    (Bb * Hh * Ss * HD)     // 4194304 per Q/K/V/AW
#define WS_ELEMS (CAN_END + 4 * TSZ)
#define WS_NEED ((size_t)WS_ELEMS * 2)

// Async global->LDS, 16B per lane. LDS dest is wave-uniform base + lane*16.
__device__ __forceinline__ void gl_lds16(const __bf16* g, __bf16* l) {
  __builtin_amdgcn_global_load_lds(
      (const __attribute__((address_space(1))) void*)g,
      (__attribute__((address_space(3))) void*)l,
      16, 0, 0);
}

// Canonicalize hs + 4 weights + 4 biases: fp32 -> contiguous bf16 workspace.
__global__ void canon_kernel(const float* hs, const float* Wq, const float* bq,
                             const float* Wk, const float* bk, const float* Wv,
                             const float* bv, const float* Wo, const float* bo,
                             __bf16* __restrict__ dst) {
  const long nchunks = CAN_END / 8;
  for (long c = blockIdx.x * blockDim.x + threadIdx.x; c < nchunks;
       c += (long)gridDim.x * blockDim.x) {
    const long i = c * 8;
    const float* src;
    long off;
    if (i < CAN_WQ)      { src = hs; off = i; }
    else if (i < CAN_BQ) { src = Wq; off = i - CAN_WQ; }
    else if (i < CAN_WK) { src = bq; off = i - CAN_BQ; }
    else if (i < CAN_BK) { src = Wk; off = i - CAN_WK; }
    else if (i < CAN_WV) { src = bk; off = i - CAN_BK; }
    else if (i < CAN_BV) { src = Wv; off = i - CAN_WV; }
    else if (i < CAN_WO) { src = bv; off = i - CAN_BV; }
    else if (i < CAN_BO) { src = Wo; off = i - CAN_WO; }
    else                 { src = bo; off = i - CAN_BO; }
    const float* s = src + off;
    bf16x8 v;
#pragma unroll
    for (int e = 0; e < 8; e++) v[e] = (__bf16)s[e];
    *(bf16x8*)(dst + i) = v;
  }
}

// ---------------------------------------------------------------------------
// GEMM: C[M=4096, N=1024(x3)] = A[M,K=1024] @ W[N,K]^T + bias (bf16 in)
// MODE 0: QKV fused, bf16 output scattered to [B,H,S,HD]
// MODE 1: out-proj, fp32 row-major output [M, D]
// 128x128 tile, BK=32, 4 waves (2x2) of 64x64, mfma 16x16x32 bf16.
// ---------------------------------------------------------------------------
template <int MODE, typename OutT>
__global__ __launch_bounds__(256, 2) void gemm_bt(
    const __bf16* __restrict__ A,
    const __bf16* __restrict__ W0, const __bf16* __restrict__ W1,
    const __bf16* __restrict__ W2,
    const __bf16* __restrict__ b0, const __bf16* __restrict__ b1,
    const __bf16* __restrict__ b2,
    OutT* __restrict__ O0, OutT* __restrict__ O1, OutT* __restrict__ O2) {
  __shared__ __align__(16) __bf16 sA[128 * 32];
  __shared__ __align__(16) __bf16 sB[128 * 32];
  const int tid = threadIdx.x;
  const int lane = tid & 63;
  const int wid = tid >> 6;
  const int quad = lane >> 4;
  const int l15 = lane & 15;
  const int mBlock = blockIdx.x * 128;

  const __bf16* W;
  const __bf16* bias;
  OutT* Out;
  int nBlock;
  if (MODE == 0) {
    const int which = blockIdx.y >> 3;  // 0:Q 1:K 2:V
    nBlock = (blockIdx.y & 7) * 128;
    W = which == 0 ? W0 : (which == 1 ? W1 : W2);
    bias = which == 0 ? b0 : (which == 1 ? b1 : b2);
    Out = which == 0 ? O0 : (which == 1 ? O1 : O2);
  } else {
    nBlock = blockIdx.y * 128;
    W = W0;
    bias = b0;
    Out = O0;
  }

  const int waveM = (wid >> 1) * 64;
  const int waveN = (wid & 1) * 64;

  f32x4 acc[4][4] = {};

  const int c1 = wid * 64 + lane;
  const int c2 = c1 + 256;
  const __bf16* Ar1 = A + (mBlock + (c1 >> 2)) * Dd + (c1 & 3) * 8;
  const __bf16* Ar2 = A + (mBlock + (c2 >> 2)) * Dd + (c2 & 3) * 8;
  const __bf16* Wr1 = W + (nBlock + (c1 >> 2)) * Dd + (c1 & 3) * 8;
  const __bf16* Wr2 = W + (nBlock + (c2 >> 2)) * Dd + (c2 & 3) * 8;
  __bf16* ldsA1 = sA + (wid * 64) * 8;
  __bf16* ldsA2 = sA + (wid * 64 + 256) * 8;
  __bf16* ldsB1 = sB + (wid * 64) * 8;
  __bf16* ldsB2 = sB + (wid * 64 + 256) * 8;

  for (int k0 = 0; k0 < Dd; k0 += 32) {
    gl_lds16(Ar1 + k0, ldsA1);
    gl_lds16(Ar2 + k0, ldsA2);
    gl_lds16(Wr1 + k0, ldsB1);
    gl_lds16(Wr2 + k0, ldsB2);
    __syncthreads();

    bf16x8 aF[4], bF[4];
#pragma unroll
    for (int mi = 0; mi < 4; mi++)
      aF[mi] = *(const bf16x8*)(sA + (waveM + mi * 16 + l15) * 32 + quad * 8);
#pragma unroll
    for (int ni = 0; ni < 4; ni++)
      bF[ni] = *(const bf16x8*)(sB + (waveN + ni * 16 + l15) * 32 + quad * 8);
#pragma unroll
    for (int mi = 0; mi < 4; mi++)
#pragma unroll
      for (int ni = 0; ni < 4; ni++)
        acc[mi][ni] = __builtin_amdgcn_mfma_f32_16x16x32_bf16(
            aF[mi], bF[ni], acc[mi][ni], 0, 0, 0);
    __syncthreads();
  }

  // C/D layout (m89-verified): col = lane&15, row = quad*4 + r.
#pragma unroll
  for (int ni = 0; ni < 4; ni++) {
    const int ng = nBlock + waveN + ni * 16 + l15;
    const float bv = (float)bias[ng];
#pragma unroll
    for (int mi = 0; mi < 4; mi++) {
      const int mg0 = mBlock + waveM + mi * 16 + quad * 4;
#pragma unroll
      for (int r = 0; r < 4; r++) {
        const float v = acc[mi][ni][r] + bv;
        const int m = mg0 + r;
        if (MODE == 0) {
          const int b = m >> 11, s = m & 2047;
          const int h = ng >> 6, hd = ng & 63;
          Out[(((b * Hh + h) * Ss + s) * HD) + hd] = (OutT)v;
        } else {
          Out[m * Dd + ng] = (OutT)v;
        }
      }
    }
  }
}

// ---------------------------------------------------------------------------
// Flash attention: block = (q-tile 128, b*h); 4 waves x 32 q-rows; KV tiles 64.
// Mask is fp32, read directly from global (L3-resident).
// ---------------------------------------------------------------------------
__global__ __launch_bounds__(256, 2) void attn_fused(
    const __bf16* __restrict__ Qg, const __bf16* __restrict__ Kg,
    const __bf16* __restrict__ Vg, const float* __restrict__ Mf,
    __bf16* __restrict__ Og) {
  __shared__ __align__(16) __bf16 sQ[2][128][32];
  __shared__ __align__(16) __bf16 sK[2][64][32];
  __shared__ __align__(16) __bf16 sVt[64][72];
  __shared__ __align__(16) __bf16 sP[4][32][72];

  const int tid = threadIdx.x;
  const int lane = tid & 63;
  const int wid = tid >> 6;
  const int quad = lane >> 4;
  const int l15 = lane & 15;
  const int bh = blockIdx.y;
  const int b = bh >> 4;
  const int q0 = blockIdx.x * 128;

  const __bf16* Qp = Qg + (size_t)bh * Ss * HD;
  const __bf16* Kp = Kg + (size_t)bh * Ss * HD;
  const __bf16* Vp = Vg + (size_t)bh * Ss * HD;
  const size_t mbase = (size_t)b * Ss * Ss + (size_t)q0 * Ss;

#pragma unroll
  for (int j = 0; j < 4; j++) {
    const int cb = j * 256 + wid * 64;
    const int c = cb + lane;
    const int hh = c >> 9, rem = c & 511;
    const int row = rem >> 2, kc = (rem & 3) * 8;
    gl_lds16(Qp + (q0 + row) * HD + hh * 32 + kc, &sQ[0][0][0] + cb * 8);
  }

  f32x4 o[2][4] = {};
  float mrun[2][4], lrun[2][4];
#pragma unroll
  for (int mi = 0; mi < 2; mi++)
#pragma unroll
    for (int r = 0; r < 4; r++) {
      mrun[mi][r] = -1e30f;
      lrun[mi][r] = 0.f;
    }

  const int qrow = wid * 32;
  const float scale = 0.125f;  // HD^-0.5

  for (int kv0 = 0; kv0 < Ss; kv0 += 64) {
#pragma unroll
    for (int j = 0; j < 2; j++) {
      const int cb = j * 256 + wid * 64;
      const int c = cb + lane;
      const int hh = c >> 8, rem = c & 255;
      const int row = rem >> 2, kc = (rem & 3) * 8;
      gl_lds16(Kp + (kv0 + row) * HD + hh * 32 + kc, &sK[0][0][0] + cb * 8);
    }
#pragma unroll
    for (int j = 0; j < 2; j++) {
      const int c = j * 256 + tid;
      const int row = c >> 3, hc = (c & 7) * 8;
      bf16x8 v = *(const bf16x8*)(Vp + (kv0 + row) * HD + hc);
#pragma unroll
      for (int e = 0; e < 8; e++) sVt[hc + e][row] = v[e];
    }
    __syncthreads();

    // S = Q K^T
    f32x4 s[2][4] = {};
#pragma unroll
    for (int ks = 0; ks < 2; ks++) {
      bf16x8 aF[2], bF[4];
#pragma unroll
      for (int mi = 0; mi < 2; mi++)
        aF[mi] = *(const bf16x8*)&sQ[ks][qrow + mi * 16 + l15][quad * 8];
#pragma unroll
      for (int ni = 0; ni < 4; ni++)
        bF[ni] = *(const bf16x8*)&sK[ks][ni * 16 + l15][quad * 8];
#pragma unroll
      for (int mi = 0; mi < 2; mi++)
#pragma unroll
        for (int ni = 0; ni < 4; ni++)
          s[mi][ni] = __builtin_amdgcn_mfma_f32_16x16x32_bf16(
              aF[mi], bF[ni], s[mi][ni], 0, 0, 0);
    }

    // scale + mask (fp32 mask, coalesced across l15 lanes)
#pragma unroll
    for (int mi = 0; mi < 2; mi++)
#pragma unroll
      for (int r = 0; r < 4; r++) {
        const int qr = qrow + mi * 16 + quad * 4 + r;
        const float* mrow = Mf + mbase + (size_t)qr * Ss + kv0;
#pragma unroll
        for (int ni = 0; ni < 4; ni++)
          s[mi][ni][r] = s[mi][ni][r] * scale + mrow[ni * 16 + l15];
      }

    // online softmax (row's 64 cols live in 16 lanes of one quad group)
#pragma unroll
    for (int mi = 0; mi < 2; mi++) {
#pragma unroll
      for (int r = 0; r < 4; r++) {
        float v = fmaxf(fmaxf(s[mi][0][r], s[mi][1][r]),
                        fmaxf(s[mi][2][r], s[mi][3][r]));
        v = fmaxf(v, __shfl_xor(v, 1));
        v = fmaxf(v, __shfl_xor(v, 2));
        v = fmaxf(v, __shfl_xor(v, 4));
        v = fmaxf(v, __shfl_xor(v, 8));
        const float mnew = fmaxf(mrun[mi][r], v);
        const float alpha = __expf(mrun[mi][r] - mnew);
        mrun[mi][r] = mnew;
        float rsum = 0.f;
#pragma unroll
        for (int ni = 0; ni < 4; ni++) {
          const float p = __expf(s[mi][ni][r] - mnew);
          rsum += p;
          s[mi][ni][r] = p;
        }
        rsum += __shfl_xor(rsum, 1);
        rsum += __shfl_xor(rsum, 2);
        rsum += __shfl_xor(rsum, 4);
        rsum += __shfl_xor(rsum, 8);
        lrun[mi][r] = lrun[mi][r] * alpha + rsum;
#pragma unroll
        for (int ni = 0; ni < 4; ni++) o[mi][ni][r] *= alpha;
      }
    }

    // P: C-layout regs -> per-wave LDS -> A-layout
#pragma unroll
    for (int mi = 0; mi < 2; mi++)
#pragma unroll
      for (int ni = 0; ni < 4; ni++)
#pragma unroll
        for (int r = 0; r < 4; r++)
          sP[wid][mi * 16 + quad * 4 + r][ni * 16 + l15] =
              (__bf16)s[mi][ni][r];

    // O += P V
#pragma unroll
    for (int ks = 0; ks < 2; ks++) {
      bf16x8 aF[2], bF[4];
#pragma unroll
      for (int mi = 0; mi < 2; mi++)
        aF[mi] = *(const bf16x8*)&sP[wid][mi * 16 + l15][ks * 32 + quad * 8];
#pragma unroll
      for (int ni = 0; ni < 4; ni++)
        bF[ni] = *(const bf16x8*)&sVt[ni * 16 + l15][ks * 32 + quad * 8];
#pragma unroll
      for (int mi = 0; mi < 2; mi++)
#pragma unroll
        for (int ni = 0; ni < 4; ni++)
          o[mi][ni] = __builtin_amdgcn_mfma_f32_16x16x32_bf16(
              aF[mi], bF[ni], o[mi][ni], 0, 0, 0);
    }
    __syncthreads();
  }

  // normalize + store to [B,S,H,HD] (bf16 intermediate for out-proj)
  const int h = bh & 15;
#pragma unroll
  for (int mi = 0; mi < 2; mi++) {
#pragma unroll
    for (int r = 0; r < 4; r++) {
      const float inv = 1.0f / lrun[mi][r];
      const int sg = q0 + qrow + mi * 16 + quad * 4 + r;
#pragma unroll
      for (int ni = 0; ni < 4; ni++) {
        Og[((size_t)(b * Ss + sg) * Hh + h) * HD + ni * 16 + l15] =
            (__bf16)(o[mi][ni][r] * inv);
      }
    }
  }
}

// ---------------------------------------------------------------------------
extern "C" void kernel_launch(void* const* d_in, const int* in_sizes, int n_in,
                              void* d_out, int out_size, void* d_ws,
                              size_t ws_size, hipStream_t stream) {
  if (ws_size < WS_NEED) return;  // diagnostic: would fail with absmax=0.249

  __bf16* ws = (__bf16*)d_ws;
  const __bf16* hsC = ws + CAN_HS;
  const __bf16* WqC = ws + CAN_WQ;
  const __bf16* bqC = ws + CAN_BQ;
  const __bf16* WkC = ws + CAN_WK;
  const __bf16* bkC = ws + CAN_BK;
  const __bf16* WvC = ws + CAN_WV;
  const __bf16* bvC = ws + CAN_BV;
  const __bf16* WoC = ws + CAN_WO;
  const __bf16* boC = ws + CAN_BO;
  __bf16* Q = ws + CAN_END;
  __bf16* K = Q + TSZ;
  __bf16* V = K + TSZ;
  __bf16* AW = V + TSZ;
  float* out = (float*)d_out;

  canon_kernel<<<2048, 256, 0, stream>>>(
      (const float*)d_in[0], (const float*)d_in[2], (const float*)d_in[3],
      (const float*)d_in[4], (const float*)d_in[5], (const float*)d_in[6],
      (const float*)d_in[7], (const float*)d_in[8], (const float*)d_in[9], ws);
  gemm_bt<0, __bf16><<<dim3(32, 24), 256, 0, stream>>>(
      hsC, WqC, WkC, WvC, bqC, bkC, bvC, Q, K, V);
  attn_fused<<<dim3(16, 32), 256, 0, stream>>>(Q, K, V, (const float*)d_in[1],
                                               AW);
  gemm_bt<1, float><<<dim3(32, 8), 256, 0, stream>>>(
      AW, WoC, WoC, WoC, boC, boC, boC, out, out, out);
}

// Round 5
// 276.810 us; speedup vs baseline: 1.2651x; 1.2651x over previous
//
#include <hip/hip_runtime.h>
#include <hip/hip_bf16.h>
#include <stdint.h>

// B=2, S=2048, D=1024, H=16, HD=64. Inputs fp32, d_out fp32 (resolved r1-r3).
// Pipeline: canon fp32->bf16; QKV GEMM (V written transposed [B,H,HD,S]);
// flash attention in S^T/O^T formulation (Q in regs, V^T direct-staged);
// out-proj GEMM -> fp32.
// r4 postmortem: canon if/else ladder had a hand-offset typo (off = i-CAN_BV
// for the Wv segment) -> negative offset -> OOB read -> device page fault.
// Replaced with a segment TABLE so the bug class is gone.
#define Bb 2
#define Ss 2048
#define Dd 1024
#define Hh 16
#define HD 64

typedef __attribute__((ext_vector_type(8))) __bf16 bf16x8;
typedef __attribute__((ext_vector_type(4))) __bf16 bf16x4;
typedef __attribute__((ext_vector_type(4))) float f32x4;

#define LOG2E 1.44269504088896f

// ---- workspace layout (bf16 elements) --------------------------------------
#define HS_N   (Bb * Ss * Dd)
#define W_N    (Dd * Dd)
#define B_N    (Dd)
#define CAN_HS 0
#define CAN_WQ (CAN_HS + HS_N)
#define CAN_BQ (CAN_WQ + W_N)
#define CAN_WK (CAN_BQ + B_N)
#define CAN_BK (CAN_WK + W_N)
#define CAN_WV (CAN_BK + B_N)
#define CAN_BV (CAN_WV + W_N)
#define CAN_WO (CAN_BV + B_N)
#define CAN_BO (CAN_WO + W_N)
#define CAN_END (CAN_BO + B_N)
#define TSZ    (Bb * Hh * Ss * HD)
#define WS_ELEMS (CAN_END + 4 * TSZ)
#define WS_NEED ((size_t)WS_ELEMS * 2)

__device__ __forceinline__ void gl_lds16(const __bf16* g, __bf16* l) {
  __builtin_amdgcn_global_load_lds(
      (const __attribute__((address_space(1))) void*)g,
      (__attribute__((address_space(3))) void*)l,
      16, 0, 0);
}

// fp32 -> bf16 canonicalization of hs + weights + biases (segment table).
__global__ void canon_kernel(const float* hs, const float* Wq, const float* bq,
                             const float* Wk, const float* bk, const float* Wv,
                             const float* bv, const float* Wo, const float* bo,
                             __bf16* __restrict__ dst) {
  const float* srcs[9] = {hs, Wq, bq, Wk, bk, Wv, bv, Wo, bo};
  const long starts[10] = {CAN_HS, CAN_WQ, CAN_BQ, CAN_WK, CAN_BK,
                           CAN_WV, CAN_BV, CAN_WO, CAN_BO, CAN_END};
  const long nchunks = CAN_END / 8;
  for (long c = blockIdx.x * blockDim.x + threadIdx.x; c < nchunks;
       c += (long)gridDim.x * blockDim.x) {
    const long i = c * 8;
    int seg = 0;
#pragma unroll
    for (int t = 1; t < 9; t++) seg += (i >= starts[t]) ? 1 : 0;
    const float* s = srcs[seg] + (i - starts[seg]);
    bf16x8 v;
#pragma unroll
    for (int e = 0; e < 8; e++) v[e] = (__bf16)s[e];
    *(bf16x8*)(dst + i) = v;
  }
}

// ---------------------------------------------------------------------------
// GEMM: C[4096, 1024(x3)] = A @ W^T + bias (bf16 in).
// MODE 0: QKV fused. Q,K -> [B,H,S,HD]; V -> TRANSPOSED [B,H,HD,S].
// MODE 1: out-proj, fp32 row-major [M, D].
// ---------------------------------------------------------------------------
template <int MODE, typename OutT>
__global__ __launch_bounds__(256, 2) void gemm_bt(
    const __bf16* __restrict__ A,
    const __bf16* __restrict__ W0, const __bf16* __restrict__ W1,
    const __bf16* __restrict__ W2,
    const __bf16* __restrict__ b0, const __bf16* __restrict__ b1,
    const __bf16* __restrict__ b2,
    OutT* __restrict__ O0, OutT* __restrict__ O1, OutT* __restrict__ O2) {
  __shared__ __align__(16) __bf16 sA[128 * 32];
  __shared__ __align__(16) __bf16 sB[128 * 32];
  const int tid = threadIdx.x;
  const int lane = tid & 63;
  const int wid = tid >> 6;
  const int quad = lane >> 4;
  const int l15 = lane & 15;
  const int mBlock = blockIdx.x * 128;

  const __bf16* W;
  const __bf16* bias;
  OutT* Out;
  int nBlock, which = 0;
  if (MODE == 0) {
    which = blockIdx.y >> 3;  // 0:Q 1:K 2:V
    nBlock = (blockIdx.y & 7) * 128;
    W = which == 0 ? W0 : (which == 1 ? W1 : W2);
    bias = which == 0 ? b0 : (which == 1 ? b1 : b2);
    Out = which == 0 ? O0 : (which == 1 ? O1 : O2);
  } else {
    nBlock = blockIdx.y * 128;
    W = W0;
    bias = b0;
    Out = O0;
  }

  const int waveM = (wid >> 1) * 64;
  const int waveN = (wid & 1) * 64;

  f32x4 acc[4][4] = {};

  const int c1 = wid * 64 + lane;
  const int c2 = c1 + 256;
  const __bf16* Ar1 = A + (mBlock + (c1 >> 2)) * Dd + (c1 & 3) * 8;
  const __bf16* Ar2 = A + (mBlock + (c2 >> 2)) * Dd + (c2 & 3) * 8;
  const __bf16* Wr1 = W + (nBlock + (c1 >> 2)) * Dd + (c1 & 3) * 8;
  const __bf16* Wr2 = W + (nBlock + (c2 >> 2)) * Dd + (c2 & 3) * 8;
  __bf16* ldsA1 = sA + (wid * 64) * 8;
  __bf16* ldsA2 = sA + (wid * 64 + 256) * 8;
  __bf16* ldsB1 = sB + (wid * 64) * 8;
  __bf16* ldsB2 = sB + (wid * 64 + 256) * 8;

  for (int k0 = 0; k0 < Dd; k0 += 32) {
    gl_lds16(Ar1 + k0, ldsA1);
    gl_lds16(Ar2 + k0, ldsA2);
    gl_lds16(Wr1 + k0, ldsB1);
    gl_lds16(Wr2 + k0, ldsB2);
    __syncthreads();

    bf16x8 aF[4], bF[4];
#pragma unroll
    for (int mi = 0; mi < 4; mi++)
      aF[mi] = *(const bf16x8*)(sA + (waveM + mi * 16 + l15) * 32 + quad * 8);
#pragma unroll
    for (int ni = 0; ni < 4; ni++)
      bF[ni] = *(const bf16x8*)(sB + (waveN + ni * 16 + l15) * 32 + quad * 8);
#pragma unroll
    for (int mi = 0; mi < 4; mi++)
#pragma unroll
      for (int ni = 0; ni < 4; ni++)
        acc[mi][ni] = __builtin_amdgcn_mfma_f32_16x16x32_bf16(
            aF[mi], bF[ni], acc[mi][ni], 0, 0, 0);
    __syncthreads();
  }

  // C/D layout: col = lane&15, row = quad*4 + r.
#pragma unroll
  for (int ni = 0; ni < 4; ni++) {
    const int ng = nBlock + waveN + ni * 16 + l15;
    const float bv = (float)bias[ng];
#pragma unroll
    for (int mi = 0; mi < 4; mi++) {
      const int mg0 = mBlock + waveM + mi * 16 + quad * 4;
#pragma unroll
      for (int r = 0; r < 4; r++) {
        const float v = acc[mi][ni][r] + bv;
        const int m = mg0 + r;
        if (MODE == 0) {
          const int b = m >> 11, s = m & 2047;
          const int h = ng >> 6, hd = ng & 63;
          if (which == 2)  // V transposed: [B,H,HD,S]
            Out[(((b * Hh + h) * HD + hd) * Ss) + s] = (OutT)v;
          else
            Out[(((b * Hh + h) * Ss + s) * HD) + hd] = (OutT)v;
        } else {
          Out[m * Dd + ng] = (OutT)v;
        }
      }
    }
  }
}

// ---------------------------------------------------------------------------
// Flash attention, transposed formulation.
//   S^T = K Q^T   (per wave: [kv 64][q 16], Q-frags in registers)
//   O^T = V^T P^T (V^T pre-transposed in global, direct-staged to LDS)
// Block: 64 q-rows, 4 waves x 16 q. Grid 32 x 32 = 1024 blocks (~4-5/CU).
// Per-lane softmax state: lane's q col = l15 (quad-replicated), reduce via
// shfl_xor(16/32). Base-2 exp with scale*log2e folded in.
// ---------------------------------------------------------------------------
__global__ __launch_bounds__(256, 4) void attn_fused(
    const __bf16* __restrict__ Qg, const __bf16* __restrict__ Kg,
    const __bf16* __restrict__ Vt, const float* __restrict__ Mf,
    __bf16* __restrict__ Og) {
  __shared__ __align__(16) __bf16 sK[2][64][32];   // [hd-half][kv][32]
  __shared__ __align__(16) __bf16 sVt[2][64][32];  // [kv-half][hd][32]
  __shared__ __align__(16) __bf16 sP[4][16][80];   // per-wave [q][kv+pad]

  const int tid = threadIdx.x;
  const int lane = tid & 63;
  const int wid = tid >> 6;
  const int quad = lane >> 4;
  const int l15 = lane & 15;
  const int bh = blockIdx.y;
  const int b = bh >> 4;
  const int h = bh & 15;
  const int q0 = blockIdx.x * 64;
  const int q = q0 + wid * 16 + l15;  // this lane's q row

  const __bf16* Qp = Qg + (size_t)bh * Ss * HD;
  const __bf16* Kp = Kg + (size_t)bh * Ss * HD;
  const __bf16* Vp = Vt + (size_t)bh * HD * Ss;  // [hd][S]
  const float* Mrow = Mf + ((size_t)b * Ss + q) * Ss;

  // Q fragments in registers for the whole kernel.
  bf16x8 qf[2];
#pragma unroll
  for (int ks = 0; ks < 2; ks++)
    qf[ks] = *(const bf16x8*)(Qp + (size_t)q * HD + ks * 32 + quad * 8);

  f32x4 o4[4] = {};     // O^T[hd = mi*16+quad*4+r][q = l15]
  float mrun = -1e30f;  // in base-2 units
  float lrun = 0.f;
  const float SCL2 = 0.125f * LOG2E;

  for (int kv0 = 0; kv0 < Ss; kv0 += 64) {
    // Mask prefetch (latency hidden behind staging + barrier).
    f32x4 m4[4];
#pragma unroll
    for (int mi = 0; mi < 4; mi++)
      m4[mi] = *(const f32x4*)(Mrow + kv0 + mi * 16 + quad * 4);

    // Stage K tile [kv 64][hd 64] -> sK[hdhalf][kv][32]; 512 chunks.
#pragma unroll
    for (int j = 0; j < 2; j++) {
      const int c = j * 256 + tid;
      const int ks = c >> 8, rem = c & 255;
      const int row = rem >> 2, kc = c & 3;
      gl_lds16(Kp + (kv0 + row) * HD + ks * 32 + kc * 8, &sK[0][0][0] + c * 8);
    }
    // Stage V^T tile [hd 64][kv 64] -> sVt[kvhalf][hd][32]; 512 chunks.
#pragma unroll
    for (int j = 0; j < 2; j++) {
      const int c = j * 256 + tid;
      const int ks = c >> 8, rem = c & 255;
      const int hd = rem >> 2, kc = c & 3;
      gl_lds16(Vp + (size_t)hd * Ss + kv0 + ks * 32 + kc * 8,
               &sVt[0][0][0] + c * 8);
    }
    __syncthreads();

    // S^T = K Q^T : s4[mi] holds S^T[kv = mi*16+quad*4+r][q = l15]
    f32x4 s4[4] = {};
#pragma unroll
    for (int ks = 0; ks < 2; ks++) {
      bf16x8 kf[4];
#pragma unroll
      for (int mi = 0; mi < 4; mi++)
        kf[mi] = *(const bf16x8*)&sK[ks][mi * 16 + l15][quad * 8];
#pragma unroll
      for (int mi = 0; mi < 4; mi++)
        s4[mi] = __builtin_amdgcn_mfma_f32_16x16x32_bf16(kf[mi], qf[ks],
                                                         s4[mi], 0, 0, 0);
    }

    // t = s*scale*log2e + mask*log2e; softmax over 16 local kv + cross-quad.
#pragma unroll
    for (int mi = 0; mi < 4; mi++)
#pragma unroll
      for (int r = 0; r < 4; r++)
        s4[mi][r] = s4[mi][r] * SCL2 + m4[mi][r] * LOG2E;

    float vmax = -1e30f;
#pragma unroll
    for (int mi = 0; mi < 4; mi++)
#pragma unroll
      for (int r = 0; r < 4; r++) vmax = fmaxf(vmax, s4[mi][r]);
    vmax = fmaxf(vmax, __shfl_xor(vmax, 16));
    vmax = fmaxf(vmax, __shfl_xor(vmax, 32));

    const float mnew = fmaxf(mrun, vmax);
    const float alpha = exp2f(mrun - mnew);
    mrun = mnew;
    float rsum = 0.f;
#pragma unroll
    for (int mi = 0; mi < 4; mi++)
#pragma unroll
      for (int r = 0; r < 4; r++) {
        const float p = exp2f(s4[mi][r] - mnew);
        rsum += p;
        s4[mi][r] = p;
      }
    rsum += __shfl_xor(rsum, 16);
    rsum += __shfl_xor(rsum, 32);
    lrun = lrun * alpha + rsum;
#pragma unroll
    for (int mi = 0; mi < 4; mi++) o4[mi] *= alpha;

    // P -> per-wave sP[q=l15][kv], packed b64 writes.
    // WAR guard: prior ds_reads of sP (other lanes' data) must drain first.
    asm volatile("s_waitcnt lgkmcnt(0)" ::: "memory");
#pragma unroll
    for (int mi = 0; mi < 4; mi++) {
      bf16x4 pk;
#pragma unroll
      for (int r = 0; r < 4; r++) pk[r] = (__bf16)s4[mi][r];
      *(bf16x4*)&sP[wid][l15][mi * 16 + quad * 4] = pk;
    }
    // RAW guard: cross-lane writes must land before B-frag reads.
    asm volatile("s_waitcnt lgkmcnt(0)" ::: "memory");

    // O^T += V^T P^T
#pragma unroll
    for (int ks = 0; ks < 2; ks++) {
      bf16x8 pf = *(const bf16x8*)&sP[wid][l15][ks * 32 + quad * 8];
      bf16x8 vf[4];
#pragma unroll
      for (int mi = 0; mi < 4; mi++)
        vf[mi] = *(const bf16x8*)&sVt[ks][mi * 16 + l15][quad * 8];
#pragma unroll
      for (int mi = 0; mi < 4; mi++)
        o4[mi] = __builtin_amdgcn_mfma_f32_16x16x32_bf16(vf[mi], pf, o4[mi],
                                                         0, 0, 0);
    }
    __syncthreads();  // protect sK/sVt before next staging
  }

  // Normalize, pack 4 consecutive hd, store to AW [B,S,H*HD].
  const float inv = 1.0f / lrun;
  __bf16* Ow = Og + (((size_t)b * Ss + q) * Hh + h) * HD;
#pragma unroll
  for (int mi = 0; mi < 4; mi++) {
    bf16x4 pk;
#pragma unroll
    for (int r = 0; r < 4; r++) pk[r] = (__bf16)(o4[mi][r] * inv);
    *(bf16x4*)(Ow + mi * 16 + quad * 4) = pk;
  }
}

// ---------------------------------------------------------------------------
extern "C" void kernel_launch(void* const* d_in, const int* in_sizes, int n_in,
                              void* d_out, int out_size, void* d_ws,
                              size_t ws_size, hipStream_t stream) {
  if (ws_size < WS_NEED) return;

  __bf16* ws = (__bf16*)d_ws;
  const __bf16* hsC = ws + CAN_HS;
  const __bf16* WqC = ws + CAN_WQ;
  const __bf16* bqC = ws + CAN_BQ;
  const __bf16* WkC = ws + CAN_WK;
  const __bf16* bkC = ws + CAN_BK;
  const __bf16* WvC = ws + CAN_WV;
  const __bf16* bvC = ws + CAN_BV;
  const __bf16* WoC = ws + CAN_WO;
  const __bf16* boC = ws + CAN_BO;
  __bf16* Q = ws + CAN_END;
  __bf16* K = Q + TSZ;
  __bf16* V = K + TSZ;  // transposed layout [B,H,HD,S]
  __bf16* AW = V + TSZ;
  float* out = (float*)d_out;

  canon_kernel<<<2048, 256, 0, stream>>>(
      (const float*)d_in[0], (const float*)d_in[2], (const float*)d_in[3],
      (const float*)d_in[4], (const float*)d_in[5], (const float*)d_in[6],
      (const float*)d_in[7], (const float*)d_in[8], (const float*)d_in[9], ws);
  gemm_bt<0, __bf16><<<dim3(32, 24), 256, 0, stream>>>(
      hsC, WqC, WkC, WvC, bqC, bkC, bvC, Q, K, V);
  attn_fused<<<dim3(32, 32), 256, 0, stream>>>(Q, K, V, (const float*)d_in[1],
                                               AW);
  gemm_bt<1, float><<<dim3(32, 8), 256, 0, stream>>>(
      AW, WoC, WoC, WoC, boC, boC, boC, out, out, out);
}